// Round 10
// baseline (1389.636 us; speedup 1.0000x reference)
//
#include <hip/hip_runtime.h>
#include <math.h>

// Problem constants
constexpr int Bb = 64;    // batch
constexpr int Pp = 400;   // passage len
constexpr int Qq = 50;    // question len
constexpr int Ee = 300;   // embed dim
constexpr int Hh = 256;   // hidden
constexpr int H3 = 768;   // 3*H
constexpr int Dd = 512;   // 2*H

#define NEGC (-10000000.0f)
#define LOGTINY (-103.278929903f)   // log(float32(1e-45)) = log(2^-149)

typedef _Float16 h2 __attribute__((ext_vector_type(2)));
typedef _Float16 f16x8 __attribute__((ext_vector_type(8)));
typedef float f32x4 __attribute__((ext_vector_type(4)));

__device__ __forceinline__ float allred(float v){
  #pragma unroll
  for (int off = 1; off < 64; off <<= 1) v += __shfl_xor(v, off);
  return v;
}
__device__ __forceinline__ float allmax(float v){
  #pragma unroll
  for (int off = 1; off < 64; off <<= 1) v = fmaxf(v, __shfl_xor(v, off));
  return v;
}
__device__ __forceinline__ float sigm(float x){ return 1.f / (1.f + expf(-x)); }

__device__ __forceinline__ float dot2f(unsigned a, unsigned b, float c){
#if __has_builtin(__builtin_amdgcn_fdot2)
  return __builtin_amdgcn_fdot2(__builtin_bit_cast(h2, a), __builtin_bit_cast(h2, b), c, false);
#else
  float r = c;
  asm("v_dot2_f32_f16 %0, %1, %2, %0" : "+v"(r) : "v"(a), "v"(b));
  return r;
#endif
}

// AGPR residency via register-CLASS constraints (not hardcoded regs):
// values defined by "=a" and consumed by "a" live in the AGPR class for
// their whole lifetime -> the VGPR allocator never owns them, so its
// spill heuristic (r2-r9: always spills big arrays) cannot touch them.
__device__ __forceinline__ unsigned to_agpr(unsigned v){
  unsigned r;
  asm volatile("v_accvgpr_write_b32 %0, %1" : "=a"(r) : "v"(v));
  return r;
}
__device__ __forceinline__ unsigned from_agpr(unsigned a){
  unsigned r;
  asm("v_accvgpr_read_b32 %0, %1" : "=v"(r) : "a"(a));
  return r;
}

// ---------------------------------------------------------------------------
// Pack Whh to fp16 pairs for the half-split owner-thread layout (r6 layout).
// u32 slot idx = ((gd*3 + gate)*16 + q)*2048 + t*4 + c, where thread
// t = half*256 + j owns pair p = half*64 + q*4 + c of row (gate*256 + j):
// value = pack(W[d][row][2p], W[d][row][2p+1]). uint4 loads coalesce in t.
// ---------------------------------------------------------------------------
__global__ __launch_bounds__(256) void prep_w16(const float* __restrict__ pW,
                                                const float* __restrict__ qW,
                                                unsigned* __restrict__ w16){
  int idx = blockIdx.x * 256 + threadIdx.x;   // u32 slot
  if (idx >= 2 * 2 * 3 * 16 * 512 * 4) return;
  int c = idx & 3;
  int t = (idx >> 2) & 511;
  int q = (idx >> 11) & 15;
  int gg = idx >> 15;            // gd*3 + gate
  int gate = gg % 3, gd = gg / 3;
  int d = gd & 1, g = gd >> 1;
  int j = t & 255, half = t >> 8;
  int p = half * 64 + q * 4 + c;
  int row = gate * 256 + j;
  const float* W = g ? qW : pW;
  const float* src = W + ((size_t)d * H3 + row) * Hh + 2 * p;
  _Float16 a = (_Float16)src[0], b = (_Float16)src[1];
  unsigned short ua, ub;
  __builtin_memcpy(&ua, &a, 2); __builtin_memcpy(&ub, &b, 2);
  w16[idx] = (unsigned)ua | ((unsigned)ub << 16);
}

// ---------------------------------------------------------------------------
// xproj via MFMA (fp16 in, fp32 acc): out[d][b][t][h] = emb[tok] @ Wih^T + b.
// ---------------------------------------------------------------------------
__global__ __launch_bounds__(512) void xproj_mfma(const int* __restrict__ tok,
                                                  const float* __restrict__ emb,
                                                  const float* __restrict__ Wih,
                                                  const float* __restrict__ bih,
                                                  float* __restrict__ xp, int T){
  __shared__ __align__(16) _Float16 As[128][72];
  __shared__ __align__(16) _Float16 Bs[128][72];
  int tid = threadIdx.x;
  int m0 = blockIdx.y * 128;
  int nt = blockIdx.x;                 // 0..11
  int d = nt / 6, h0 = (nt % 6) * 128;
  int wid = tid >> 6, lane = tid & 63;
  int wr = wid >> 2, wc = wid & 3;

  int srow = tid >> 2;                 // 0..127
  int scol = (tid & 3) * 16;           // 0,16,32,48
  const float* aRow = emb + (size_t)tok[m0 + srow] * Ee;
  const float* bRow = Wih + ((size_t)d * H3 + h0 + srow) * Ee;

  f32x4 acc[4][2] = {};

  for (int k0 = 0; k0 < 320; k0 += 64){
    #pragma unroll
    for (int half = 0; half < 2; ++half){
      int k = k0 + scol + half * 8;
      float4 va0, va1, vb0, vb1;
      if (k + 8 <= Ee){
        va0 = *(const float4*)(aRow + k); va1 = *(const float4*)(aRow + k + 4);
        vb0 = *(const float4*)(bRow + k); vb1 = *(const float4*)(bRow + k + 4);
      } else if (k + 4 <= Ee){
        va0 = *(const float4*)(aRow + k); va1 = make_float4(0.f, 0.f, 0.f, 0.f);
        vb0 = *(const float4*)(bRow + k); vb1 = make_float4(0.f, 0.f, 0.f, 0.f);
      } else {
        va0 = va1 = vb0 = vb1 = make_float4(0.f, 0.f, 0.f, 0.f);
      }
      f16x8 a8 = { (_Float16)va0.x, (_Float16)va0.y, (_Float16)va0.z, (_Float16)va0.w,
                   (_Float16)va1.x, (_Float16)va1.y, (_Float16)va1.z, (_Float16)va1.w };
      f16x8 b8 = { (_Float16)vb0.x, (_Float16)vb0.y, (_Float16)vb0.z, (_Float16)vb0.w,
                   (_Float16)vb1.x, (_Float16)vb1.y, (_Float16)vb1.z, (_Float16)vb1.w };
      *(f16x8*)&As[srow][scol + half * 8] = a8;
      *(f16x8*)&Bs[srow][scol + half * 8] = b8;
    }
    __syncthreads();
    #pragma unroll
    for (int kc = 0; kc < 2; ++kc){
      int kb = kc * 32 + (lane >> 4) * 8;
      f16x8 af[4], bf[2];
      #pragma unroll
      for (int i = 0; i < 4; ++i) af[i] = *(const f16x8*)&As[wr * 64 + i * 16 + (lane & 15)][kb];
      #pragma unroll
      for (int jn = 0; jn < 2; ++jn) bf[jn] = *(const f16x8*)&Bs[wc * 32 + jn * 16 + (lane & 15)][kb];
      #pragma unroll
      for (int i = 0; i < 4; ++i)
        #pragma unroll
        for (int jn = 0; jn < 2; ++jn)
          acc[i][jn] = __builtin_amdgcn_mfma_f32_16x16x32_f16(af[i], bf[jn], acc[i][jn], 0, 0, 0);
    }
    __syncthreads();
  }

  #pragma unroll
  for (int jn = 0; jn < 2; ++jn){
    int h = h0 + wc * 32 + jn * 16 + (lane & 15);
    float bv = bih[d * H3 + h];
    #pragma unroll
    for (int i = 0; i < 4; ++i){
      #pragma unroll
      for (int r = 0; r < 4; ++r){
        int m = m0 + wr * 64 + i * 16 + (lane >> 4) * 4 + r;
        int bI = m / T, tI = m - bI * T;
        xp[(((size_t)d * Bb + bI) * T + tI) * H3 + h] = acc[i][jn][r] + bv;
      }
    }
  }
}

// ---------------------------------------------------------------------------
// AGPR-resident GRU (half-split, r6 structure). 256 WGs x 512 threads.
// Thread t = half*256 + j owns 3x64 fp16-pair weight words held in the AGPR
// register class ("a" constraints). 100 KB LDS pad keeps 1 WG/CU so the
// unified budget is 256 regs/wave: 192 AGPR weights + ~60 VGPR working.
// Per step: readlane h-broadcast + accvgpr_read + v_dot2, gates on half 0.
// ---------------------------------------------------------------------------
__global__ __launch_bounds__(512, 2) __attribute__((amdgpu_waves_per_eu(2, 2)))
void gru_kernel(const int* __restrict__ ptok,
                const int* __restrict__ qtok,
                const float* __restrict__ xpp,
                const float* __restrict__ xpq,
                const unsigned* __restrict__ w16,
                const float* __restrict__ pbhh,
                const float* __restrict__ qbhh,
                float* __restrict__ Hp,
                float* __restrict__ Hq){
  int wg = blockIdx.x;
  bool isp = wg < 128;
  int lw = isp ? wg : wg - 128;
  int d = lw & 1, b = lw >> 1;
  int T = isp ? Pp : Qq;
  const int* tok = (isp ? ptok : qtok) + b * T;
  const float* xrow = (isp ? xpp : xpq) + ((size_t)d * Bb + b) * T * H3;
  int gd = (isp ? 0 : 2) + d;
  const float* bhh = (isp ? pbhh : qbhh) + d * H3;
  float* Hout = (isp ? Hp : Hq) + (size_t)b * T * Dd + d * Hh;

  // 25600 floats = 100 KB: occupancy pad -> 1 WG/CU -> 2 waves/SIMD.
  __shared__ __align__(16) float shmem[25600];
  unsigned (*hbuf)[128] = (unsigned(*)[128])shmem;   // [2][128] packed fp16 h
  float* pa = shmem + 256;
  float* pb = shmem + 512;
  float* pn = shmem + 768;

  int t = threadIdx.x;
  int j = t & 255, half = t >> 8, lane = t & 63;

  unsigned w0[64], w1[64], w2[64];
  {
    const uint4* wq = (const uint4*)w16 + (size_t)gd * 3 * 16 * 512;
    #pragma unroll
    for (int q = 0; q < 16; ++q){
      uint4 v0 = wq[(0 * 16 + q) * 512 + t];
      uint4 v1 = wq[(1 * 16 + q) * 512 + t];
      uint4 v2 = wq[(2 * 16 + q) * 512 + t];
      w0[4 * q + 0] = to_agpr(v0.x); w0[4 * q + 1] = to_agpr(v0.y);
      w0[4 * q + 2] = to_agpr(v0.z); w0[4 * q + 3] = to_agpr(v0.w);
      w1[4 * q + 0] = to_agpr(v1.x); w1[4 * q + 1] = to_agpr(v1.y);
      w1[4 * q + 2] = to_agpr(v1.z); w1[4 * q + 3] = to_agpr(v1.w);
      w2[4 * q + 0] = to_agpr(v2.x); w2[4 * q + 1] = to_agpr(v2.y);
      w2[4 * q + 2] = to_agpr(v2.z); w2[4 * q + 3] = to_agpr(v2.w);
    }
  }

  float bh0 = bhh[j], bh1 = bhh[Hh + j], bh2 = bhh[2 * Hh + j];
  float h_old = 0.f;
  if (t < 128) hbuf[1][t] = 0u;     // step 0 reads buf[1]
  __syncthreads();

  int t0 = d ? (T - 1) : 0;
  float pre0 = 0.f, pre1 = 0.f, pre2 = 0.f;
  if (half == 0){
    pre0 = xrow[(size_t)t0 * H3 + j];
    pre1 = xrow[(size_t)t0 * H3 + Hh + j];
    pre2 = xrow[(size_t)t0 * H3 + 2 * Hh + j];
  }

  for (int s = 0; s < T; ++s){
    int tt = d ? (T - 1 - s) : s;
    unsigned vh = hbuf[(s + 1) & 1][half * 64 + lane];
    float a0 = 0.f, a1 = 0.f, a2 = 0.f;
    #pragma unroll
    for (int p = 0; p < 64; ++p){
      unsigned hv = (unsigned)__builtin_amdgcn_readlane((int)vh, p);
      a0 = dot2f(from_agpr(w0[p]), hv, a0);
      a1 = dot2f(from_agpr(w1[p]), hv, a1);
      a2 = dot2f(from_agpr(w2[p]), hv, a2);
    }
    if (half == 1){ pa[j] = a0; pb[j] = a1; pn[j] = a2; }
    __syncthreads();
    if (half == 0){
      float xt0 = pre0, xt1 = pre1, xt2 = pre2;
      if (s + 1 < T){
        int tn = d ? (T - 2 - s) : (s + 1);
        pre0 = xrow[(size_t)tn * H3 + j];
        pre1 = xrow[(size_t)tn * H3 + Hh + j];
        pre2 = xrow[(size_t)tn * H3 + 2 * Hh + j];
      }
      float g0 = a0 + pa[j] + bh0;
      float g1 = a1 + pb[j] + bh1;
      float g2 = a2 + pn[j] + bh2;
      float r = sigm(xt0 + g0);
      float z = sigm(xt1 + g1);
      float n = tanhf(xt2 + r * g2);
      float hnew = (1.f - z) * n + z * h_old;
      float m = (tok[tt] != 0) ? 1.f : 0.f;
      float hm = m * hnew + (1.f - m) * h_old;
      h_old = hm;
      ((_Float16*)hbuf[s & 1])[j] = (_Float16)hm;
      Hout[(size_t)tt * Dd + j] = hm * m;
    }
    __syncthreads();
  }
}

// ---------------------------------------------------------------------------
// Attention + logits (unchanged)
// ---------------------------------------------------------------------------
__global__ __launch_bounds__(512) void attn_kernel(const float* __restrict__ Hp,
                                                   const float* __restrict__ Hq,
                                                   const int* __restrict__ ptok,
                                                   const int* __restrict__ qtok,
                                                   const float* __restrict__ start_w,
                                                   const float* __restrict__ sbp,
                                                   const float* __restrict__ end_w,
                                                   const float* __restrict__ ebp,
                                                   float* __restrict__ out){
  extern __shared__ __align__(16) float lds[];
  float* hqs = lds;               // 50*512
  float* s2s = hqs + Qq * Dd;     // 64
  float* qms = s2s + 64;          // 64
  float* scw = qms + 64;          // 8*64
  float* aw  = scw + 512;         // 8*64

  int b = blockIdx.y, pc = blockIdx.x;
  int tid = threadIdx.x, wid = tid >> 6, lane = tid & 63;
  float sb = sbp[0], eb = ebp[0];

  float w1r[8], w2r[8], w3r[8], e1r[8], e2r[8], e3r[8];
  #pragma unroll
  for (int i = 0; i < 8; ++i){
    int c = lane * 8 + i;
    w1r[i] = start_w[c]; w2r[i] = start_w[Dd + c]; w3r[i] = start_w[2 * Dd + c];
    e1r[i] = end_w[c];   e2r[i] = end_w[Dd + c];   e3r[i] = end_w[2 * Dd + c];
  }
  for (int idx = tid; idx < Qq * Dd; idx += 512) hqs[idx] = Hq[(size_t)b * Qq * Dd + idx];
  __syncthreads();

  for (int q = wid; q < Qq; q += 8){
    float part = 0.f;
    const float* hq = hqs + q * Dd + lane * 8;
    #pragma unroll
    for (int i = 0; i < 8; ++i) part += hq[i] * w2r[i];
    part = allred(part);
    if (lane == 0){
      s2s[q] = part;
      qms[q] = (qtok[b * Qq + q] != 0) ? 1.f : 0.f;
    }
  }
  __syncthreads();

  for (int p = pc * 100 + wid; p < pc * 100 + 100; p += 8){
    const float* hprow = Hp + ((size_t)b * Pp + p) * Dd + lane * 8;
    float4 hv0 = *(const float4*)hprow;
    float4 hv1 = *(const float4*)(hprow + 4);
    float hpc[8] = {hv0.x, hv0.y, hv0.z, hv0.w, hv1.x, hv1.y, hv1.z, hv1.w};
    float hw3[8], he3[8];
    float s1 = 0.f, ed = 0.f;
    #pragma unroll
    for (int i = 0; i < 8; ++i){
      hw3[i] = hpc[i] * w3r[i];
      he3[i] = hpc[i] * e3r[i];
      s1 += hpc[i] * w1r[i];
      ed += hpc[i] * e1r[i];
    }
    #pragma unroll
    for (int off = 1; off < 64; off <<= 1){
      s1 += __shfl_xor(s1, off);
      ed += __shfl_xor(ed, off);
    }
    for (int q = 0; q < Qq; ++q){
      const float4* hq4 = (const float4*)(hqs + q * Dd + lane * 8);
      float4 a0 = hq4[0], a1 = hq4[1];
      float dot = hw3[0] * a0.x + hw3[1] * a0.y + hw3[2] * a0.z + hw3[3] * a0.w
                + hw3[4] * a1.x + hw3[5] * a1.y + hw3[6] * a1.z + hw3[7] * a1.w;
      dot = allred(dot);
      if (lane == 0) scw[wid * 64 + q] = (s1 + s2s[q] + dot + sb) * qms[q];
    }
    float v = (lane < Qq) ? scw[wid * 64 + lane] : -1e30f;
    float M = allmax(v);
    float ev = (lane < Qq) ? expf(v - M) : 0.f;
    float S = allred(ev);
    float am = (lane < Qq) ? (ev / S) * qms[lane] : 0.f;
    float Sm = allred(am);
    float af = am / (Sm + 1e-13f);
    if (lane < Qq) aw[wid * 64 + lane] = af;
    float wv[8] = {0.f, 0.f, 0.f, 0.f, 0.f, 0.f, 0.f, 0.f};
    for (int q = 0; q < Qq; ++q){
      float aq = aw[wid * 64 + q];
      const float4* hq4 = (const float4*)(hqs + q * Dd + lane * 8);
      float4 a0 = hq4[0], a1 = hq4[1];
      wv[0] += aq * a0.x; wv[1] += aq * a0.y; wv[2] += aq * a0.z; wv[3] += aq * a0.w;
      wv[4] += aq * a1.x; wv[5] += aq * a1.y; wv[6] += aq * a1.z; wv[7] += aq * a1.w;
    }
    float acc2 = 0.f, acc3 = 0.f, acc4 = 0.f, acc5 = 0.f;
    #pragma unroll
    for (int i = 0; i < 8; ++i){
      acc2 += wv[i] * w2r[i];
      acc3 += hw3[i] * wv[i];
      acc4 += wv[i] * e2r[i];
      acc5 += he3[i] * wv[i];
    }
    #pragma unroll
    for (int off = 1; off < 64; off <<= 1){
      acc2 += __shfl_xor(acc2, off);
      acc3 += __shfl_xor(acc3, off);
      acc4 += __shfl_xor(acc4, off);
      acc5 += __shfl_xor(acc5, off);
    }
    if (lane == 0){
      bool pm = (ptok[b * Pp + p] != 0);
      out[(size_t)b * Pp + p]                   = pm ? (s1 + acc2 + acc3 + sb) : NEGC;
      out[(size_t)Bb * Pp + (size_t)b * Pp + p] = pm ? (ed + acc4 + acc5 + eb) : NEGC;
    }
  }
}

// ---------------------------------------------------------------------------
// log_softmax over p (unchanged)
// ---------------------------------------------------------------------------
__global__ __launch_bounds__(512) void lsm_kernel(const int* __restrict__ ptok,
                                                  float* __restrict__ out){
  int b = blockIdx.x >> 1, sel = blockIdx.x & 1;
  const float* lg = out + (size_t)sel * Bb * Pp + (size_t)b * Pp;
  float* o = out + (size_t)(2 + sel) * Bb * Pp + (size_t)b * Pp;
  int tid = threadIdx.x;
  __shared__ float red1[8];
  __shared__ float red2[8];
  float x = -1e30f;
  if (tid < Pp) x = lg[tid] + ((ptok[b * Pp + tid] != 0) ? 0.f : LOGTINY);
  float m = allmax(x);
  if ((tid & 63) == 0) red1[tid >> 6] = m;
  __syncthreads();
  float M = red1[0];
  #pragma unroll
  for (int i = 1; i < 8; ++i) M = fmaxf(M, red1[i]);
  float e = (tid < Pp) ? expf(x - M) : 0.f;
  float s = allred(e);
  if ((tid & 63) == 0) red2[tid >> 6] = s;
  __syncthreads();
  float S = 0.f;
  #pragma unroll
  for (int i = 0; i < 8; ++i) S += red2[i];
  if (tid < Pp) o[tid] = (x - M) - logf(S);
}

// ---------------------------------------------------------------------------
extern "C" void kernel_launch(void* const* d_in, const int* in_sizes, int n_in,
                              void* d_out, int out_size, void* d_ws, size_t ws_size,
                              hipStream_t stream){
  const int*   passage  = (const int*)d_in[0];
  const int*   question = (const int*)d_in[1];
  const float* emb      = (const float*)d_in[2];
  const float* pW_ih    = (const float*)d_in[3];
  const float* pW_hh    = (const float*)d_in[4];
  const float* pb_ih    = (const float*)d_in[5];
  const float* pb_hh    = (const float*)d_in[6];
  const float* qW_ih    = (const float*)d_in[7];
  const float* qW_hh    = (const float*)d_in[8];
  const float* qb_ih    = (const float*)d_in[9];
  const float* qb_hh    = (const float*)d_in[10];
  const float* start_w  = (const float*)d_in[11];
  const float* start_b  = (const float*)d_in[12];
  const float* end_w    = (const float*)d_in[13];
  const float* end_b    = (const float*)d_in[14];
  float* out = (float*)d_out;

  // workspace layout (float-sized units)
  float*    ws  = (float*)d_ws;
  unsigned* w16 = (unsigned*)ws;            //   393216 u32 : packed fp16 Whh
  float*    xpp = ws + 393216;              // 39321600 : [d][b][t][768]
  float*    xpq = ws + 39714816;            //  4915200
  float*    Hp  = ws + 44630016;            // 13107200 : [b][t][512]
  float*    Hq  = ws + 57737216;            //  1638400
  // total 59,375,616 floats = 237.5 MB

  hipLaunchKernelGGL(prep_w16, dim3(1536), dim3(256), 0, stream, pW_hh, qW_hh, w16);
  hipLaunchKernelGGL(xproj_mfma, dim3(12, 200), dim3(512), 0, stream,
                     passage, emb, pW_ih, pb_ih, xpp, Pp);
  hipLaunchKernelGGL(xproj_mfma, dim3(12, 25), dim3(512), 0, stream,
                     question, emb, qW_ih, qb_ih, xpq, Qq);
  hipLaunchKernelGGL(gru_kernel, dim3(256), dim3(512), 0, stream,
                     passage, question, xpp, xpq, w16, pb_hh, qb_hh, Hp, Hq);
  size_t attn_lds = (size_t)(Qq * Dd + 64 + 64 + 512 + 512) * sizeof(float);
  hipLaunchKernelGGL(attn_kernel, dim3(4, 64), dim3(512), attn_lds, stream,
                     Hp, Hq, passage, question, start_w, start_b, end_w, end_b, out);
  hipLaunchKernelGGL(lsm_kernel, dim3(128), dim3(512), 0, stream, passage, out);
}

// Round 11
// 972.813 us; speedup vs baseline: 1.4285x; 1.4285x over previous
//
#include <hip/hip_runtime.h>
#include <math.h>

// Problem constants
constexpr int Bb = 64;    // batch
constexpr int Pp = 400;   // passage len
constexpr int Qq = 50;    // question len
constexpr int Ee = 300;   // embed dim
constexpr int Hh = 256;   // hidden
constexpr int H3 = 768;   // 3*H
constexpr int Dd = 512;   // 2*H

#define NEGC (-10000000.0f)
#define LOGTINY (-103.278929903f)   // log(float32(1e-45)) = log(2^-149)

typedef _Float16 h2 __attribute__((ext_vector_type(2)));
typedef _Float16 f16x8 __attribute__((ext_vector_type(8)));
typedef float f32x4 __attribute__((ext_vector_type(4)));

__device__ __forceinline__ float allred(float v){
  #pragma unroll
  for (int off = 1; off < 64; off <<= 1) v += __shfl_xor(v, off);
  return v;
}
__device__ __forceinline__ float allmax(float v){
  #pragma unroll
  for (int off = 1; off < 64; off <<= 1) v = fmaxf(v, __shfl_xor(v, off));
  return v;
}
__device__ __forceinline__ float sigm(float x){ return 1.f / (1.f + expf(-x)); }

__device__ __forceinline__ float dot2f(unsigned a, unsigned b, float c){
#if __has_builtin(__builtin_amdgcn_fdot2)
  return __builtin_amdgcn_fdot2(__builtin_bit_cast(h2, a), __builtin_bit_cast(h2, b), c, false);
#else
  float r = c;
  asm("v_dot2_f32_f16 %0, %1, %2, %0" : "+v"(r) : "v"(a), "v"(b));
  return r;
#endif
}

#define U4C(v,c) ((c)==0?(v).x:((c)==1?(v).y:((c)==2?(v).z:(v).w)))

// ---------------------------------------------------------------------------
// Pack Whh to fp16 pairs, 3-tier destination layout (uint4 units):
//   R (reg tier,   q 0..3 ): [gg][4][512]  base 0       (24576 uint4)
//   L (LDS tier,   q 4..9 ): [gg][6][512]  base 24576   (36864 uint4)
//   S (stream tier,q 10..15): [gg][6][512] base 61440   (36864 uint4)
// gg = gd*3 + gate, gd = kind*2 + d. Thread t = half*256 + j owns pair
// p = half*64 + q*4 + c of row gate*256 + j: pack(W[d][row][2p],W[d][row][2p+1]).
// ---------------------------------------------------------------------------
__global__ __launch_bounds__(256) void prep_w16(const float* __restrict__ pW,
                                                const float* __restrict__ qW,
                                                unsigned* __restrict__ w16){
  int idx = blockIdx.x * 256 + threadIdx.x;   // u32 slot id (393216 total)
  if (idx >= 2 * 2 * 3 * 16 * 512 * 4) return;
  int c = idx & 3;
  int t = (idx >> 2) & 511;
  int q = (idx >> 11) & 15;
  int gg = idx >> 15;            // gd*3 + gate
  int gate = gg % 3, gd = gg / 3;
  int d = gd & 1, g = gd >> 1;
  int j = t & 255, half = t >> 8;
  int p = half * 64 + q * 4 + c;
  int row = gate * 256 + j;
  const float* W = g ? qW : pW;
  const float* src = W + ((size_t)d * H3 + row) * Hh + 2 * p;
  _Float16 a = (_Float16)src[0], b = (_Float16)src[1];
  unsigned short ua, ub;
  __builtin_memcpy(&ua, &a, 2); __builtin_memcpy(&ub, &b, 2);
  unsigned val = (unsigned)ua | ((unsigned)ub << 16);

  size_t u4idx;
  if (q < 4)       u4idx = ((size_t)gg * 4 + q) * 512 + t;
  else if (q < 10) u4idx = 24576 + ((size_t)gg * 6 + (q - 4)) * 512 + t;
  else             u4idx = 61440 + ((size_t)gg * 6 + (q - 10)) * 512 + t;
  w16[u4idx * 4 + c] = val;
}

// ---------------------------------------------------------------------------
// xproj via MFMA (fp16 in, fp32 acc, fp16 OUT): xp[d][b][t][h] (half).
// ---------------------------------------------------------------------------
__global__ __launch_bounds__(512) void xproj_mfma(const int* __restrict__ tok,
                                                  const float* __restrict__ emb,
                                                  const float* __restrict__ Wih,
                                                  const float* __restrict__ bih,
                                                  _Float16* __restrict__ xp, int T){
  __shared__ __align__(16) _Float16 As[128][72];
  __shared__ __align__(16) _Float16 Bs[128][72];
  int tid = threadIdx.x;
  int m0 = blockIdx.y * 128;
  int nt = blockIdx.x;                 // 0..11
  int d = nt / 6, h0 = (nt % 6) * 128;
  int wid = tid >> 6, lane = tid & 63;
  int wr = wid >> 2, wc = wid & 3;

  int srow = tid >> 2;                 // 0..127
  int scol = (tid & 3) * 16;           // 0,16,32,48
  const float* aRow = emb + (size_t)tok[m0 + srow] * Ee;
  const float* bRow = Wih + ((size_t)d * H3 + h0 + srow) * Ee;

  f32x4 acc[4][2] = {};

  for (int k0 = 0; k0 < 320; k0 += 64){
    #pragma unroll
    for (int half = 0; half < 2; ++half){
      int k = k0 + scol + half * 8;
      float4 va0, va1, vb0, vb1;
      if (k + 8 <= Ee){
        va0 = *(const float4*)(aRow + k); va1 = *(const float4*)(aRow + k + 4);
        vb0 = *(const float4*)(bRow + k); vb1 = *(const float4*)(bRow + k + 4);
      } else if (k + 4 <= Ee){
        va0 = *(const float4*)(aRow + k); va1 = make_float4(0.f, 0.f, 0.f, 0.f);
        vb0 = *(const float4*)(bRow + k); vb1 = make_float4(0.f, 0.f, 0.f, 0.f);
      } else {
        va0 = va1 = vb0 = vb1 = make_float4(0.f, 0.f, 0.f, 0.f);
      }
      f16x8 a8 = { (_Float16)va0.x, (_Float16)va0.y, (_Float16)va0.z, (_Float16)va0.w,
                   (_Float16)va1.x, (_Float16)va1.y, (_Float16)va1.z, (_Float16)va1.w };
      f16x8 b8 = { (_Float16)vb0.x, (_Float16)vb0.y, (_Float16)vb0.z, (_Float16)vb0.w,
                   (_Float16)vb1.x, (_Float16)vb1.y, (_Float16)vb1.z, (_Float16)vb1.w };
      *(f16x8*)&As[srow][scol + half * 8] = a8;
      *(f16x8*)&Bs[srow][scol + half * 8] = b8;
    }
    __syncthreads();
    #pragma unroll
    for (int kc = 0; kc < 2; ++kc){
      int kb = kc * 32 + (lane >> 4) * 8;
      f16x8 af[4], bf[2];
      #pragma unroll
      for (int i = 0; i < 4; ++i) af[i] = *(const f16x8*)&As[wr * 64 + i * 16 + (lane & 15)][kb];
      #pragma unroll
      for (int jn = 0; jn < 2; ++jn) bf[jn] = *(const f16x8*)&Bs[wc * 32 + jn * 16 + (lane & 15)][kb];
      #pragma unroll
      for (int i = 0; i < 4; ++i)
        #pragma unroll
        for (int jn = 0; jn < 2; ++jn)
          acc[i][jn] = __builtin_amdgcn_mfma_f32_16x16x32_f16(af[i], bf[jn], acc[i][jn], 0, 0, 0);
    }
    __syncthreads();
  }

  #pragma unroll
  for (int jn = 0; jn < 2; ++jn){
    int h = h0 + wc * 32 + jn * 16 + (lane & 15);
    float bv = bih[d * H3 + h];
    #pragma unroll
    for (int i = 0; i < 4; ++i){
      #pragma unroll
      for (int r = 0; r < 4; ++r){
        int m = m0 + wr * 64 + i * 16 + (lane >> 4) * 4 + r;
        int bI = m / T, tI = m - bI * T;
        xp[(((size_t)d * Bb + bI) * T + tI) * H3 + h] = (_Float16)(acc[i][jn][r] + bv);
      }
    }
  }
}

// ---------------------------------------------------------------------------
// 3-tier GRU (half-split, r6 structure). 256 WGs x 512 threads.
// Thread t = half*256 + j owns 192 weight u32 split: 48 in registers,
// 72 staged in LDS (144 KB, written once), 72 streamed from L2 per step
// (per-gate phases with next-gate prefetch to bound live pressure).
// ---------------------------------------------------------------------------
__global__ __launch_bounds__(512)
void gru_kernel(const int* __restrict__ ptok,
                const int* __restrict__ qtok,
                const _Float16* __restrict__ xpp,
                const _Float16* __restrict__ xpq,
                const unsigned* __restrict__ w16,
                const float* __restrict__ pbhh,
                const float* __restrict__ qbhh,
                float* __restrict__ Hp,
                float* __restrict__ Hq){
  int wg = blockIdx.x;
  bool isp = wg < 128;
  int lw = isp ? wg : wg - 128;
  int d = lw & 1, b = lw >> 1;
  int T = isp ? Pp : Qq;
  const int* tok = (isp ? ptok : qtok) + b * T;
  const _Float16* xrow = (isp ? xpp : xpq) + ((size_t)d * Bb + b) * T * H3;
  int gd = (isp ? 0 : 2) + d;
  const float* bhh = (isp ? pbhh : qbhh) + d * H3;
  float* Hout = (isp ? Hp : Hq) + (size_t)b * T * Dd + d * Hh;

  __shared__ __align__(16) uint4 ldsW[18 * 512];   // 147456 B, LDS weight tier
  __shared__ unsigned hbuf[2][128];                // packed fp16 h, double-buffered
  __shared__ float pa[Hh], pb[Hh], pn[Hh];

  int t = threadIdx.x;
  int j = t & 255, half = t >> 8, lane = t & 63;

  // --- init: reg tier (48 u32), LDS tier (18 uint4), stream base ---
  const uint4* wR = (const uint4*)w16 + (size_t)(gd * 3) * 4 * 512;
  unsigned wr0[16], wr1[16], wr2[16];
  #pragma unroll
  for (int q = 0; q < 4; ++q){
    uint4 v0 = wR[(0 * 4 + q) * 512 + t];
    uint4 v1 = wR[(1 * 4 + q) * 512 + t];
    uint4 v2 = wR[(2 * 4 + q) * 512 + t];
    wr0[4 * q + 0] = v0.x; wr0[4 * q + 1] = v0.y; wr0[4 * q + 2] = v0.z; wr0[4 * q + 3] = v0.w;
    wr1[4 * q + 0] = v1.x; wr1[4 * q + 1] = v1.y; wr1[4 * q + 2] = v1.z; wr1[4 * q + 3] = v1.w;
    wr2[4 * q + 0] = v2.x; wr2[4 * q + 1] = v2.y; wr2[4 * q + 2] = v2.z; wr2[4 * q + 3] = v2.w;
  }
  #pragma unroll
  for (int i = 0; i < 16; ++i){
    asm volatile("" : "+v"(wr0[i]));
    asm volatile("" : "+v"(wr1[i]));
    asm volatile("" : "+v"(wr2[i]));
  }
  const uint4* wL = (const uint4*)w16 + 24576 + (size_t)(gd * 3) * 6 * 512;
  #pragma unroll
  for (int u = 0; u < 18; ++u) ldsW[u * 512 + t] = wL[u * 512 + t];
  const uint4* wS = (const uint4*)w16 + 61440 + (size_t)(gd * 3) * 6 * 512;

  float bh0 = bhh[j], bh1 = bhh[Hh + j], bh2 = bhh[2 * Hh + j];
  float h_old = 0.f;
  if (t < 128) hbuf[1][t] = 0u;     // step 0 reads buf[1]
  __syncthreads();

  int t0 = d ? (T - 1) : 0;
  float pre0 = 0.f, pre1 = 0.f, pre2 = 0.f;
  if (half == 0){
    pre0 = (float)xrow[(size_t)t0 * H3 + j];
    pre1 = (float)xrow[(size_t)t0 * H3 + Hh + j];
    pre2 = (float)xrow[(size_t)t0 * H3 + 2 * Hh + j];
  }

  for (int s = 0; s < T; ++s){
    int tt = d ? (T - 1 - s) : s;
    unsigned vh = hbuf[(s + 1) & 1][half * 64 + lane];
    float a0 = 0.f, a1 = 0.f, a2 = 0.f;

    // issue gate-0 stream loads (in flight across R+L phases)
    uint4 sA0 = wS[0 * 512 + t], sA1 = wS[1 * 512 + t], sA2 = wS[2 * 512 + t],
          sA3 = wS[3 * 512 + t], sA4 = wS[4 * 512 + t], sA5 = wS[5 * 512 + t];

    // phase R: pairs [0,16)
    #pragma unroll
    for (int q = 0; q < 4; ++q)
      #pragma unroll
      for (int c = 0; c < 4; ++c){
        unsigned hv = (unsigned)__builtin_amdgcn_readlane((int)vh, q * 4 + c);
        a0 = dot2f(wr0[4 * q + c], hv, a0);
        a1 = dot2f(wr1[4 * q + c], hv, a1);
        a2 = dot2f(wr2[4 * q + c], hv, a2);
      }

    // phase L: pairs [16,40) from LDS
    #pragma unroll
    for (int qb = 0; qb < 6; ++qb){
      uint4 l0 = ldsW[(0 * 6 + qb) * 512 + t];
      uint4 l1 = ldsW[(1 * 6 + qb) * 512 + t];
      uint4 l2 = ldsW[(2 * 6 + qb) * 512 + t];
      #pragma unroll
      for (int c = 0; c < 4; ++c){
        unsigned hv = (unsigned)__builtin_amdgcn_readlane((int)vh, 16 + qb * 4 + c);
        a0 = dot2f(U4C(l0, c), hv, a0);
        a1 = dot2f(U4C(l1, c), hv, a1);
        a2 = dot2f(U4C(l2, c), hv, a2);
      }
    }

    // phase S: pairs [40,64) — per-gate, prefetch next gate before consume
    #define CONS(v, qi, ACC) { _Pragma("unroll") \
      for (int c = 0; c < 4; ++c){ \
        unsigned hv = (unsigned)__builtin_amdgcn_readlane((int)vh, 40 + (qi) * 4 + c); \
        ACC = dot2f(U4C(v, c), hv, ACC); } }
    uint4 sB0 = wS[6 * 512 + t],  sB1 = wS[7 * 512 + t],  sB2 = wS[8 * 512 + t],
          sB3 = wS[9 * 512 + t],  sB4 = wS[10 * 512 + t], sB5 = wS[11 * 512 + t];
    CONS(sA0, 0, a0) CONS(sA1, 1, a0) CONS(sA2, 2, a0)
    CONS(sA3, 3, a0) CONS(sA4, 4, a0) CONS(sA5, 5, a0)
    uint4 sC0 = wS[12 * 512 + t], sC1 = wS[13 * 512 + t], sC2 = wS[14 * 512 + t],
          sC3 = wS[15 * 512 + t], sC4 = wS[16 * 512 + t], sC5 = wS[17 * 512 + t];
    CONS(sB0, 0, a1) CONS(sB1, 1, a1) CONS(sB2, 2, a1)
    CONS(sB3, 3, a1) CONS(sB4, 4, a1) CONS(sB5, 5, a1)
    CONS(sC0, 0, a2) CONS(sC1, 1, a2) CONS(sC2, 2, a2)
    CONS(sC3, 3, a2) CONS(sC4, 4, a2) CONS(sC5, 5, a2)
    #undef CONS

    if (half == 1){ pa[j] = a0; pb[j] = a1; pn[j] = a2; }
    __syncthreads();
    if (half == 0){
      float xt0 = pre0, xt1 = pre1, xt2 = pre2;
      if (s + 1 < T){
        int tn = d ? (T - 2 - s) : (s + 1);
        pre0 = (float)xrow[(size_t)tn * H3 + j];
        pre1 = (float)xrow[(size_t)tn * H3 + Hh + j];
        pre2 = (float)xrow[(size_t)tn * H3 + 2 * Hh + j];
      }
      float g0 = a0 + pa[j] + bh0;
      float g1 = a1 + pb[j] + bh1;
      float g2 = a2 + pn[j] + bh2;
      float r = sigm(xt0 + g0);
      float z = sigm(xt1 + g1);
      float n = tanhf(xt2 + r * g2);
      float hnew = (1.f - z) * n + z * h_old;
      float m = (tok[tt] != 0) ? 1.f : 0.f;
      float hm = m * hnew + (1.f - m) * h_old;
      h_old = hm;
      ((_Float16*)hbuf[s & 1])[j] = (_Float16)hm;
      Hout[(size_t)tt * Dd + j] = hm * m;
    }
    __syncthreads();
  }
}

// ---------------------------------------------------------------------------
// Attention + logits (unchanged)
// ---------------------------------------------------------------------------
__global__ __launch_bounds__(512) void attn_kernel(const float* __restrict__ Hp,
                                                   const float* __restrict__ Hq,
                                                   const int* __restrict__ ptok,
                                                   const int* __restrict__ qtok,
                                                   const float* __restrict__ start_w,
                                                   const float* __restrict__ sbp,
                                                   const float* __restrict__ end_w,
                                                   const float* __restrict__ ebp,
                                                   float* __restrict__ out){
  extern __shared__ __align__(16) float lds[];
  float* hqs = lds;               // 50*512
  float* s2s = hqs + Qq * Dd;     // 64
  float* qms = s2s + 64;          // 64
  float* scw = qms + 64;          // 8*64
  float* aw  = scw + 512;         // 8*64

  int b = blockIdx.y, pc = blockIdx.x;
  int tid = threadIdx.x, wid = tid >> 6, lane = tid & 63;
  float sb = sbp[0], eb = ebp[0];

  float w1r[8], w2r[8], w3r[8], e1r[8], e2r[8], e3r[8];
  #pragma unroll
  for (int i = 0; i < 8; ++i){
    int c = lane * 8 + i;
    w1r[i] = start_w[c]; w2r[i] = start_w[Dd + c]; w3r[i] = start_w[2 * Dd + c];
    e1r[i] = end_w[c];   e2r[i] = end_w[Dd + c];   e3r[i] = end_w[2 * Dd + c];
  }
  for (int idx = tid; idx < Qq * Dd; idx += 512) hqs[idx] = Hq[(size_t)b * Qq * Dd + idx];
  __syncthreads();

  for (int q = wid; q < Qq; q += 8){
    float part = 0.f;
    const float* hq = hqs + q * Dd + lane * 8;
    #pragma unroll
    for (int i = 0; i < 8; ++i) part += hq[i] * w2r[i];
    part = allred(part);
    if (lane == 0){
      s2s[q] = part;
      qms[q] = (qtok[b * Qq + q] != 0) ? 1.f : 0.f;
    }
  }
  __syncthreads();

  for (int p = pc * 100 + wid; p < pc * 100 + 100; p += 8){
    const float* hprow = Hp + ((size_t)b * Pp + p) * Dd + lane * 8;
    float4 hv0 = *(const float4*)hprow;
    float4 hv1 = *(const float4*)(hprow + 4);
    float hpc[8] = {hv0.x, hv0.y, hv0.z, hv0.w, hv1.x, hv1.y, hv1.z, hv1.w};
    float hw3[8], he3[8];
    float s1 = 0.f, ed = 0.f;
    #pragma unroll
    for (int i = 0; i < 8; ++i){
      hw3[i] = hpc[i] * w3r[i];
      he3[i] = hpc[i] * e3r[i];
      s1 += hpc[i] * w1r[i];
      ed += hpc[i] * e1r[i];
    }
    #pragma unroll
    for (int off = 1; off < 64; off <<= 1){
      s1 += __shfl_xor(s1, off);
      ed += __shfl_xor(ed, off);
    }
    for (int q = 0; q < Qq; ++q){
      const float4* hq4 = (const float4*)(hqs + q * Dd + lane * 8);
      float4 a0 = hq4[0], a1 = hq4[1];
      float dot = hw3[0] * a0.x + hw3[1] * a0.y + hw3[2] * a0.z + hw3[3] * a0.w
                + hw3[4] * a1.x + hw3[5] * a1.y + hw3[6] * a1.z + hw3[7] * a1.w;
      dot = allred(dot);
      if (lane == 0) scw[wid * 64 + q] = (s1 + s2s[q] + dot + sb) * qms[q];
    }
    float v = (lane < Qq) ? scw[wid * 64 + lane] : -1e30f;
    float M = allmax(v);
    float ev = (lane < Qq) ? expf(v - M) : 0.f;
    float S = allred(ev);
    float am = (lane < Qq) ? (ev / S) * qms[lane] : 0.f;
    float Sm = allred(am);
    float af = am / (Sm + 1e-13f);
    if (lane < Qq) aw[wid * 64 + lane] = af;
    float wv[8] = {0.f, 0.f, 0.f, 0.f, 0.f, 0.f, 0.f, 0.f};
    for (int q = 0; q < Qq; ++q){
      float aq = aw[wid * 64 + q];
      const float4* hq4 = (const float4*)(hqs + q * Dd + lane * 8);
      float4 a0 = hq4[0], a1 = hq4[1];
      wv[0] += aq * a0.x; wv[1] += aq * a0.y; wv[2] += aq * a0.z; wv[3] += aq * a0.w;
      wv[4] += aq * a1.x; wv[5] += aq * a1.y; wv[6] += aq * a1.z; wv[7] += aq * a1.w;
    }
    float acc2 = 0.f, acc3 = 0.f, acc4 = 0.f, acc5 = 0.f;
    #pragma unroll
    for (int i = 0; i < 8; ++i){
      acc2 += wv[i] * w2r[i];
      acc3 += hw3[i] * wv[i];
      acc4 += wv[i] * e2r[i];
      acc5 += he3[i] * wv[i];
    }
    #pragma unroll
    for (int off = 1; off < 64; off <<= 1){
      acc2 += __shfl_xor(acc2, off);
      acc3 += __shfl_xor(acc3, off);
      acc4 += __shfl_xor(acc4, off);
      acc5 += __shfl_xor(acc5, off);
    }
    if (lane == 0){
      bool pm = (ptok[b * Pp + p] != 0);
      out[(size_t)b * Pp + p]                   = pm ? (s1 + acc2 + acc3 + sb) : NEGC;
      out[(size_t)Bb * Pp + (size_t)b * Pp + p] = pm ? (ed + acc4 + acc5 + eb) : NEGC;
    }
  }
}

// ---------------------------------------------------------------------------
// log_softmax over p (unchanged)
// ---------------------------------------------------------------------------
__global__ __launch_bounds__(512) void lsm_kernel(const int* __restrict__ ptok,
                                                  float* __restrict__ out){
  int b = blockIdx.x >> 1, sel = blockIdx.x & 1;
  const float* lg = out + (size_t)sel * Bb * Pp + (size_t)b * Pp;
  float* o = out + (size_t)(2 + sel) * Bb * Pp + (size_t)b * Pp;
  int tid = threadIdx.x;
  __shared__ float red1[8];
  __shared__ float red2[8];
  float x = -1e30f;
  if (tid < Pp) x = lg[tid] + ((ptok[b * Pp + tid] != 0) ? 0.f : LOGTINY);
  float m = allmax(x);
  if ((tid & 63) == 0) red1[tid >> 6] = m;
  __syncthreads();
  float M = red1[0];
  #pragma unroll
  for (int i = 1; i < 8; ++i) M = fmaxf(M, red1[i]);
  float e = (tid < Pp) ? expf(x - M) : 0.f;
  float s = allred(e);
  if ((tid & 63) == 0) red2[tid >> 6] = s;
  __syncthreads();
  float S = 0.f;
  #pragma unroll
  for (int i = 0; i < 8; ++i) S += red2[i];
  if (tid < Pp) o[tid] = (x - M) - logf(S);
}

// ---------------------------------------------------------------------------
extern "C" void kernel_launch(void* const* d_in, const int* in_sizes, int n_in,
                              void* d_out, int out_size, void* d_ws, size_t ws_size,
                              hipStream_t stream){
  const int*   passage  = (const int*)d_in[0];
  const int*   question = (const int*)d_in[1];
  const float* emb      = (const float*)d_in[2];
  const float* pW_ih    = (const float*)d_in[3];
  const float* pW_hh    = (const float*)d_in[4];
  const float* pb_ih    = (const float*)d_in[5];
  const float* pb_hh    = (const float*)d_in[6];
  const float* qW_ih    = (const float*)d_in[7];
  const float* qW_hh    = (const float*)d_in[8];
  const float* qb_ih    = (const float*)d_in[9];
  const float* qb_hh    = (const float*)d_in[10];
  const float* start_w  = (const float*)d_in[11];
  const float* start_b  = (const float*)d_in[12];
  const float* end_w    = (const float*)d_in[13];
  const float* end_b    = (const float*)d_in[14];
  float* out = (float*)d_out;

  // workspace layout (float-sized units)
  float*     ws  = (float*)d_ws;
  unsigned*  w16 = (unsigned*)ws;                     //   393216 u32 (3-tier Whh)
  _Float16*  xpp = (_Float16*)(ws + 393216);          // 39321600 halfs = 19660800 f
  _Float16*  xpq = (_Float16*)(ws + 20054016);        //  4915200 halfs =  2457600 f
  float*     Hp  = ws + 22511616;                     // 13107200
  float*     Hq  = ws + 35618816;                     //  1638400
  // total 37,257,216 floats = 149 MB

  hipLaunchKernelGGL(prep_w16, dim3(1536), dim3(256), 0, stream, pW_hh, qW_hh, w16);
  hipLaunchKernelGGL(xproj_mfma, dim3(12, 200), dim3(512), 0, stream,
                     passage, emb, pW_ih, pb_ih, xpp, Pp);
  hipLaunchKernelGGL(xproj_mfma, dim3(12, 25), dim3(512), 0, stream,
                     question, emb, qW_ih, qb_ih, xpq, Qq);
  hipLaunchKernelGGL(gru_kernel, dim3(256), dim3(512), 0, stream,
                     passage, question, xpp, xpq, w16, pb_hh, qb_hh, Hp, Hq);
  size_t attn_lds = (size_t)(Qq * Dd + 64 + 64 + 512 + 512) * sizeof(float);
  hipLaunchKernelGGL(attn_kernel, dim3(4, 64), dim3(512), attn_lds, stream,
                     Hp, Hq, passage, question, start_w, start_b, end_w, end_b, out);
  hipLaunchKernelGGL(lsm_kernel, dim3(128), dim3(512), 0, stream, passage, out);
}

// Round 12
// 964.279 us; speedup vs baseline: 1.4411x; 1.0088x over previous
//
#include <hip/hip_runtime.h>
#include <math.h>

// Problem constants
constexpr int Bb = 64;    // batch
constexpr int Pp = 400;   // passage len
constexpr int Qq = 50;    // question len
constexpr int Ee = 300;   // embed dim
constexpr int Hh = 256;   // hidden
constexpr int H3 = 768;   // 3*H
constexpr int Dd = 512;   // 2*H

#define NEGC (-10000000.0f)
#define LOGTINY (-103.278929903f)   // log(float32(1e-45)) = log(2^-149)

typedef _Float16 h2 __attribute__((ext_vector_type(2)));
typedef _Float16 f16x8 __attribute__((ext_vector_type(8)));
typedef float f32x4 __attribute__((ext_vector_type(4)));

__device__ __forceinline__ float allred(float v){
  #pragma unroll
  for (int off = 1; off < 64; off <<= 1) v += __shfl_xor(v, off);
  return v;
}
__device__ __forceinline__ float allmax(float v){
  #pragma unroll
  for (int off = 1; off < 64; off <<= 1) v = fmaxf(v, __shfl_xor(v, off));
  return v;
}
__device__ __forceinline__ float sigm(float x){ return 1.f / (1.f + expf(-x)); }

__device__ __forceinline__ float dot2f(unsigned a, unsigned b, float c){
#if __has_builtin(__builtin_amdgcn_fdot2)
  return __builtin_amdgcn_fdot2(__builtin_bit_cast(h2, a), __builtin_bit_cast(h2, b), c, false);
#else
  float r = c;
  asm("v_dot2_f32_f16 %0, %1, %2, %0" : "+v"(r) : "v"(a), "v"(b));
  return r;
#endif
}

#define U4C(v,c) ((c)==0?(v).x:((c)==1?(v).y:((c)==2?(v).z:(v).w)))

// ---------------------------------------------------------------------------
// prep_emb16: emb fp32 [V][300] -> fp16 [V][320] zero-padded (16B-aligned rows)
// ---------------------------------------------------------------------------
__global__ __launch_bounds__(256) void prep_emb16(const float* __restrict__ emb,
                                                  _Float16* __restrict__ emb16){
  size_t idx = (size_t)blockIdx.x * 256 + threadIdx.x;   // pair id
  if (idx >= (size_t)100000 * 160) return;
  int col2 = (int)(idx % 160);
  size_t row = idx / 160;
  int c = col2 * 2;
  float2 v = make_float2(0.f, 0.f);
  if (c < Ee) v = *(const float2*)(emb + row * Ee + c);
  h2 o = { (_Float16)v.x, (_Float16)v.y };
  *(h2*)(emb16 + row * 320 + c) = o;
}

// ---------------------------------------------------------------------------
// prep_wih16: Wih fp32 [g][d][768][300] -> fp16 [g][d][768][320] padded
// ---------------------------------------------------------------------------
__global__ __launch_bounds__(256) void prep_wih16(const float* __restrict__ pW,
                                                  const float* __restrict__ qW,
                                                  _Float16* __restrict__ wih16){
  int idx = blockIdx.x * 256 + threadIdx.x;   // pair id: 2*2*768*160
  if (idx >= 2 * 2 * 768 * 160) return;
  int col2 = idx % 160;
  int r = idx / 160;           // g*1536 + d*768 + h
  int g = r / 1536;
  int dh = r % 1536;           // d*768+h
  int c = col2 * 2;
  const float* W = g ? qW : pW;
  float2 v = make_float2(0.f, 0.f);
  if (c < Ee) v = *(const float2*)(W + (size_t)dh * Ee + c);
  h2 o = { (_Float16)v.x, (_Float16)v.y };
  *(h2*)(wih16 + (size_t)r * 320 + c) = o;
}

// ---------------------------------------------------------------------------
// Pack Whh to fp16 pairs, 3-tier destination layout (uint4 units) [r11].
// ---------------------------------------------------------------------------
__global__ __launch_bounds__(256) void prep_w16(const float* __restrict__ pW,
                                                const float* __restrict__ qW,
                                                unsigned* __restrict__ w16){
  int idx = blockIdx.x * 256 + threadIdx.x;   // u32 slot id (393216 total)
  if (idx >= 2 * 2 * 3 * 16 * 512 * 4) return;
  int c = idx & 3;
  int t = (idx >> 2) & 511;
  int q = (idx >> 11) & 15;
  int gg = idx >> 15;            // gd*3 + gate
  int gate = gg % 3, gd = gg / 3;
  int d = gd & 1, g = gd >> 1;
  int j = t & 255, half = t >> 8;
  int p = half * 64 + q * 4 + c;
  int row = gate * 256 + j;
  const float* W = g ? qW : pW;
  const float* src = W + ((size_t)d * H3 + row) * Hh + 2 * p;
  _Float16 a = (_Float16)src[0], b = (_Float16)src[1];
  unsigned short ua, ub;
  __builtin_memcpy(&ua, &a, 2); __builtin_memcpy(&ub, &b, 2);
  unsigned val = (unsigned)ua | ((unsigned)ub << 16);

  size_t u4idx;
  if (q < 4)       u4idx = ((size_t)gg * 4 + q) * 512 + t;
  else if (q < 10) u4idx = 24576 + ((size_t)gg * 6 + (q - 4)) * 512 + t;
  else             u4idx = 61440 + ((size_t)gg * 6 + (q - 10)) * 512 + t;
  w16[u4idx * 4 + c] = val;
}

// ---------------------------------------------------------------------------
// xproj via MFMA, all-fp16 inputs (pre-converted, K padded to 320):
// pure f16x8 staging, no cvt, no bounds checks. xp fp16 out.
// ---------------------------------------------------------------------------
__global__ __launch_bounds__(512) void xproj_mfma(const int* __restrict__ tok,
                                                  const _Float16* __restrict__ emb16,
                                                  const _Float16* __restrict__ wih16,
                                                  const float* __restrict__ bih,
                                                  _Float16* __restrict__ xp, int T){
  __shared__ __align__(16) _Float16 Af[128][72];
  __shared__ __align__(16) _Float16 Bf[128][72];
  int tid = threadIdx.x;
  int m0 = blockIdx.y * 128;
  int nt = blockIdx.x;                 // 0..11
  int d = nt / 6, h0 = (nt % 6) * 128;
  int wid = tid >> 6, lane = tid & 63;
  int wr = wid >> 2, wc = wid & 3;

  // two staging chunks per thread per tile (A and B each)
  int r0 = tid >> 3;                    // 0..63
  int r1 = (tid + 512) >> 3;            // 64..127
  int cc = (tid & 7) * 8;               // fp16 col of 8-chunk
  const _Float16* eA0 = emb16 + (size_t)tok[m0 + r0] * 320;
  const _Float16* eA1 = emb16 + (size_t)tok[m0 + r1] * 320;
  const _Float16* wB0 = wih16 + ((size_t)d * H3 + h0 + r0) * 320;
  const _Float16* wB1 = wih16 + ((size_t)d * H3 + h0 + r1) * 320;

  f32x4 acc[4][2] = {};

  for (int k0 = 0; k0 < 320; k0 += 64){
    *(f16x8*)&Af[r0][cc] = *(const f16x8*)(eA0 + k0 + cc);
    *(f16x8*)&Af[r1][cc] = *(const f16x8*)(eA1 + k0 + cc);
    *(f16x8*)&Bf[r0][cc] = *(const f16x8*)(wB0 + k0 + cc);
    *(f16x8*)&Bf[r1][cc] = *(const f16x8*)(wB1 + k0 + cc);
    __syncthreads();
    #pragma unroll
    for (int kc = 0; kc < 2; ++kc){
      int kb = kc * 32 + (lane >> 4) * 8;
      f16x8 af[4], bf[2];
      #pragma unroll
      for (int i = 0; i < 4; ++i) af[i] = *(const f16x8*)&Af[wr * 64 + i * 16 + (lane & 15)][kb];
      #pragma unroll
      for (int jn = 0; jn < 2; ++jn) bf[jn] = *(const f16x8*)&Bf[wc * 32 + jn * 16 + (lane & 15)][kb];
      #pragma unroll
      for (int i = 0; i < 4; ++i)
        #pragma unroll
        for (int jn = 0; jn < 2; ++jn)
          acc[i][jn] = __builtin_amdgcn_mfma_f32_16x16x32_f16(af[i], bf[jn], acc[i][jn], 0, 0, 0);
    }
    __syncthreads();
  }

  #pragma unroll
  for (int jn = 0; jn < 2; ++jn){
    int h = h0 + wc * 32 + jn * 16 + (lane & 15);
    float bv = bih[d * H3 + h];
    #pragma unroll
    for (int i = 0; i < 4; ++i){
      #pragma unroll
      for (int r = 0; r < 4; ++r){
        int m = m0 + wr * 64 + i * 16 + (lane >> 4) * 4 + r;
        int bI = m / T, tI = m - bI * T;
        xp[(((size_t)d * Bb + bI) * T + tI) * H3 + h] = (_Float16)(acc[i][jn][r] + bv);
      }
    }
  }
}

// ---------------------------------------------------------------------------
// 3-tier GRU (r11) with earlier stream issue: group A at loop top, B before
// phase R, C before phase L -> every stream load has >=1 compute phase in
// flight behind it before consumption.
// ---------------------------------------------------------------------------
__global__ __launch_bounds__(512)
void gru_kernel(const int* __restrict__ ptok,
                const int* __restrict__ qtok,
                const _Float16* __restrict__ xpp,
                const _Float16* __restrict__ xpq,
                const unsigned* __restrict__ w16,
                const float* __restrict__ pbhh,
                const float* __restrict__ qbhh,
                float* __restrict__ Hp,
                float* __restrict__ Hq){
  int wg = blockIdx.x;
  bool isp = wg < 128;
  int lw = isp ? wg : wg - 128;
  int d = lw & 1, b = lw >> 1;
  int T = isp ? Pp : Qq;
  const int* tok = (isp ? ptok : qtok) + b * T;
  const _Float16* xrow = (isp ? xpp : xpq) + ((size_t)d * Bb + b) * T * H3;
  int gd = (isp ? 0 : 2) + d;
  const float* bhh = (isp ? pbhh : qbhh) + d * H3;
  float* Hout = (isp ? Hp : Hq) + (size_t)b * T * Dd + d * Hh;

  __shared__ __align__(16) uint4 ldsW[18 * 512];   // 147456 B, LDS weight tier
  __shared__ unsigned hbuf[2][128];                // packed fp16 h, double-buffered
  __shared__ float pa[Hh], pb[Hh], pn[Hh];

  int t = threadIdx.x;
  int j = t & 255, half = t >> 8, lane = t & 63;

  // --- init: reg tier (48 u32), LDS tier (18 uint4), stream base ---
  const uint4* wR = (const uint4*)w16 + (size_t)(gd * 3) * 4 * 512;
  unsigned wr0[16], wr1[16], wr2[16];
  #pragma unroll
  for (int q = 0; q < 4; ++q){
    uint4 v0 = wR[(0 * 4 + q) * 512 + t];
    uint4 v1 = wR[(1 * 4 + q) * 512 + t];
    uint4 v2 = wR[(2 * 4 + q) * 512 + t];
    wr0[4 * q + 0] = v0.x; wr0[4 * q + 1] = v0.y; wr0[4 * q + 2] = v0.z; wr0[4 * q + 3] = v0.w;
    wr1[4 * q + 0] = v1.x; wr1[4 * q + 1] = v1.y; wr1[4 * q + 2] = v1.z; wr1[4 * q + 3] = v1.w;
    wr2[4 * q + 0] = v2.x; wr2[4 * q + 1] = v2.y; wr2[4 * q + 2] = v2.z; wr2[4 * q + 3] = v2.w;
  }
  #pragma unroll
  for (int i = 0; i < 16; ++i){
    asm volatile("" : "+v"(wr0[i]));
    asm volatile("" : "+v"(wr1[i]));
    asm volatile("" : "+v"(wr2[i]));
  }
  const uint4* wL = (const uint4*)w16 + 24576 + (size_t)(gd * 3) * 6 * 512;
  #pragma unroll
  for (int u = 0; u < 18; ++u) ldsW[u * 512 + t] = wL[u * 512 + t];
  const uint4* wS = (const uint4*)w16 + 61440 + (size_t)(gd * 3) * 6 * 512;

  float bh0 = bhh[j], bh1 = bhh[Hh + j], bh2 = bhh[2 * Hh + j];
  float h_old = 0.f;
  if (t < 128) hbuf[1][t] = 0u;     // step 0 reads buf[1]
  __syncthreads();

  int t0 = d ? (T - 1) : 0;
  float pre0 = 0.f, pre1 = 0.f, pre2 = 0.f;
  if (half == 0){
    pre0 = (float)xrow[(size_t)t0 * H3 + j];
    pre1 = (float)xrow[(size_t)t0 * H3 + Hh + j];
    pre2 = (float)xrow[(size_t)t0 * H3 + 2 * Hh + j];
  }

  for (int s = 0; s < T; ++s){
    int tt = d ? (T - 1 - s) : s;
    unsigned vh = hbuf[(s + 1) & 1][half * 64 + lane];
    float a0 = 0.f, a1 = 0.f, a2 = 0.f;

    // stream issue: A and B up front (consumed after R+L phases)
    uint4 sA0 = wS[0 * 512 + t], sA1 = wS[1 * 512 + t], sA2 = wS[2 * 512 + t],
          sA3 = wS[3 * 512 + t], sA4 = wS[4 * 512 + t], sA5 = wS[5 * 512 + t];
    uint4 sB0 = wS[6 * 512 + t],  sB1 = wS[7 * 512 + t],  sB2 = wS[8 * 512 + t],
          sB3 = wS[9 * 512 + t],  sB4 = wS[10 * 512 + t], sB5 = wS[11 * 512 + t];

    // phase R: pairs [0,16)
    #pragma unroll
    for (int q = 0; q < 4; ++q)
      #pragma unroll
      for (int c = 0; c < 4; ++c){
        unsigned hv = (unsigned)__builtin_amdgcn_readlane((int)vh, q * 4 + c);
        a0 = dot2f(wr0[4 * q + c], hv, a0);
        a1 = dot2f(wr1[4 * q + c], hv, a1);
        a2 = dot2f(wr2[4 * q + c], hv, a2);
      }

    // stream issue: C (consumed after L phase + A/B consumption)
    uint4 sC0 = wS[12 * 512 + t], sC1 = wS[13 * 512 + t], sC2 = wS[14 * 512 + t],
          sC3 = wS[15 * 512 + t], sC4 = wS[16 * 512 + t], sC5 = wS[17 * 512 + t];

    // phase L: pairs [16,40) from LDS
    #pragma unroll
    for (int qb = 0; qb < 6; ++qb){
      uint4 l0 = ldsW[(0 * 6 + qb) * 512 + t];
      uint4 l1 = ldsW[(1 * 6 + qb) * 512 + t];
      uint4 l2 = ldsW[(2 * 6 + qb) * 512 + t];
      #pragma unroll
      for (int c = 0; c < 4; ++c){
        unsigned hv = (unsigned)__builtin_amdgcn_readlane((int)vh, 16 + qb * 4 + c);
        a0 = dot2f(U4C(l0, c), hv, a0);
        a1 = dot2f(U4C(l1, c), hv, a1);
        a2 = dot2f(U4C(l2, c), hv, a2);
      }
    }

    // phase S: pairs [40,64)
    #define CONS(v, qi, ACC) { _Pragma("unroll") \
      for (int c = 0; c < 4; ++c){ \
        unsigned hv = (unsigned)__builtin_amdgcn_readlane((int)vh, 40 + (qi) * 4 + c); \
        ACC = dot2f(U4C(v, c), hv, ACC); } }
    CONS(sA0, 0, a0) CONS(sA1, 1, a0) CONS(sA2, 2, a0)
    CONS(sA3, 3, a0) CONS(sA4, 4, a0) CONS(sA5, 5, a0)
    CONS(sB0, 0, a1) CONS(sB1, 1, a1) CONS(sB2, 2, a1)
    CONS(sB3, 3, a1) CONS(sB4, 4, a1) CONS(sB5, 5, a1)
    CONS(sC0, 0, a2) CONS(sC1, 1, a2) CONS(sC2, 2, a2)
    CONS(sC3, 3, a2) CONS(sC4, 4, a2) CONS(sC5, 5, a2)
    #undef CONS

    if (half == 1){ pa[j] = a0; pb[j] = a1; pn[j] = a2; }
    __syncthreads();
    if (half == 0){
      float xt0 = pre0, xt1 = pre1, xt2 = pre2;
      if (s + 1 < T){
        int tn = d ? (T - 2 - s) : (s + 1);
        pre0 = (float)xrow[(size_t)tn * H3 + j];
        pre1 = (float)xrow[(size_t)tn * H3 + Hh + j];
        pre2 = (float)xrow[(size_t)tn * H3 + 2 * Hh + j];
      }
      float g0 = a0 + pa[j] + bh0;
      float g1 = a1 + pb[j] + bh1;
      float g2 = a2 + pn[j] + bh2;
      float r = sigm(xt0 + g0);
      float z = sigm(xt1 + g1);
      float n = tanhf(xt2 + r * g2);
      float hnew = (1.f - z) * n + z * h_old;
      float m = (tok[tt] != 0) ? 1.f : 0.f;
      float hm = m * hnew + (1.f - m) * h_old;
      h_old = hm;
      ((_Float16*)hbuf[s & 1])[j] = (_Float16)hm;
      Hout[(size_t)tt * Dd + j] = hm * m;
    }
    __syncthreads();
  }
}

// ---------------------------------------------------------------------------
// Attention + logits (unchanged)
// ---------------------------------------------------------------------------
__global__ __launch_bounds__(512) void attn_kernel(const float* __restrict__ Hp,
                                                   const float* __restrict__ Hq,
                                                   const int* __restrict__ ptok,
                                                   const int* __restrict__ qtok,
                                                   const float* __restrict__ start_w,
                                                   const float* __restrict__ sbp,
                                                   const float* __restrict__ end_w,
                                                   const float* __restrict__ ebp,
                                                   float* __restrict__ out){
  extern __shared__ __align__(16) float lds[];
  float* hqs = lds;               // 50*512
  float* s2s = hqs + Qq * Dd;     // 64
  float* qms = s2s + 64;          // 64
  float* scw = qms + 64;          // 8*64
  float* aw  = scw + 512;         // 8*64

  int b = blockIdx.y, pc = blockIdx.x;
  int tid = threadIdx.x, wid = tid >> 6, lane = tid & 63;
  float sb = sbp[0], eb = ebp[0];

  float w1r[8], w2r[8], w3r[8], e1r[8], e2r[8], e3r[8];
  #pragma unroll
  for (int i = 0; i < 8; ++i){
    int c = lane * 8 + i;
    w1r[i] = start_w[c]; w2r[i] = start_w[Dd + c]; w3r[i] = start_w[2 * Dd + c];
    e1r[i] = end_w[c];   e2r[i] = end_w[Dd + c];   e3r[i] = end_w[2 * Dd + c];
  }
  for (int idx = tid; idx < Qq * Dd; idx += 512) hqs[idx] = Hq[(size_t)b * Qq * Dd + idx];
  __syncthreads();

  for (int q = wid; q < Qq; q += 8){
    float part = 0.f;
    const float* hq = hqs + q * Dd + lane * 8;
    #pragma unroll
    for (int i = 0; i < 8; ++i) part += hq[i] * w2r[i];
    part = allred(part);
    if (lane == 0){
      s2s[q] = part;
      qms[q] = (qtok[b * Qq + q] != 0) ? 1.f : 0.f;
    }
  }
  __syncthreads();

  for (int p = pc * 100 + wid; p < pc * 100 + 100; p += 8){
    const float* hprow = Hp + ((size_t)b * Pp + p) * Dd + lane * 8;
    float4 hv0 = *(const float4*)hprow;
    float4 hv1 = *(const float4*)(hprow + 4);
    float hpc[8] = {hv0.x, hv0.y, hv0.z, hv0.w, hv1.x, hv1.y, hv1.z, hv1.w};
    float hw3[8], he3[8];
    float s1 = 0.f, ed = 0.f;
    #pragma unroll
    for (int i = 0; i < 8; ++i){
      hw3[i] = hpc[i] * w3r[i];
      he3[i] = hpc[i] * e3r[i];
      s1 += hpc[i] * w1r[i];
      ed += hpc[i] * e1r[i];
    }
    #pragma unroll
    for (int off = 1; off < 64; off <<= 1){
      s1 += __shfl_xor(s1, off);
      ed += __shfl_xor(ed, off);
    }
    for (int q = 0; q < Qq; ++q){
      const float4* hq4 = (const float4*)(hqs + q * Dd + lane * 8);
      float4 a0 = hq4[0], a1 = hq4[1];
      float dot = hw3[0] * a0.x + hw3[1] * a0.y + hw3[2] * a0.z + hw3[3] * a0.w
                + hw3[4] * a1.x + hw3[5] * a1.y + hw3[6] * a1.z + hw3[7] * a1.w;
      dot = allred(dot);
      if (lane == 0) scw[wid * 64 + q] = (s1 + s2s[q] + dot + sb) * qms[q];
    }
    float v = (lane < Qq) ? scw[wid * 64 + lane] : -1e30f;
    float M = allmax(v);
    float ev = (lane < Qq) ? expf(v - M) : 0.f;
    float S = allred(ev);
    float am = (lane < Qq) ? (ev / S) * qms[lane] : 0.f;
    float Sm = allred(am);
    float af = am / (Sm + 1e-13f);
    if (lane < Qq) aw[wid * 64 + lane] = af;
    float wv[8] = {0.f, 0.f, 0.f, 0.f, 0.f, 0.f, 0.f, 0.f};
    for (int q = 0; q < Qq; ++q){
      float aq = aw[wid * 64 + q];
      const float4* hq4 = (const float4*)(hqs + q * Dd + lane * 8);
      float4 a0 = hq4[0], a1 = hq4[1];
      wv[0] += aq * a0.x; wv[1] += aq * a0.y; wv[2] += aq * a0.z; wv[3] += aq * a0.w;
      wv[4] += aq * a1.x; wv[5] += aq * a1.y; wv[6] += aq * a1.z; wv[7] += aq * a1.w;
    }
    float acc2 = 0.f, acc3 = 0.f, acc4 = 0.f, acc5 = 0.f;
    #pragma unroll
    for (int i = 0; i < 8; ++i){
      acc2 += wv[i] * w2r[i];
      acc3 += hw3[i] * wv[i];
      acc4 += wv[i] * e2r[i];
      acc5 += he3[i] * wv[i];
    }
    #pragma unroll
    for (int off = 1; off < 64; off <<= 1){
      acc2 += __shfl_xor(acc2, off);
      acc3 += __shfl_xor(acc3, off);
      acc4 += __shfl_xor(acc4, off);
      acc5 += __shfl_xor(acc5, off);
    }
    if (lane == 0){
      bool pm = (ptok[b * Pp + p] != 0);
      out[(size_t)b * Pp + p]                   = pm ? (s1 + acc2 + acc3 + sb) : NEGC;
      out[(size_t)Bb * Pp + (size_t)b * Pp + p] = pm ? (ed + acc4 + acc5 + eb) : NEGC;
    }
  }
}

// ---------------------------------------------------------------------------
// log_softmax over p (unchanged)
// ---------------------------------------------------------------------------
__global__ __launch_bounds__(512) void lsm_kernel(const int* __restrict__ ptok,
                                                  float* __restrict__ out){
  int b = blockIdx.x >> 1, sel = blockIdx.x & 1;
  const float* lg = out + (size_t)sel * Bb * Pp + (size_t)b * Pp;
  float* o = out + (size_t)(2 + sel) * Bb * Pp + (size_t)b * Pp;
  int tid = threadIdx.x;
  __shared__ float red1[8];
  __shared__ float red2[8];
  float x = -1e30f;
  if (tid < Pp) x = lg[tid] + ((ptok[b * Pp + tid] != 0) ? 0.f : LOGTINY);
  float m = allmax(x);
  if ((tid & 63) == 0) red1[tid >> 6] = m;
  __syncthreads();
  float M = red1[0];
  #pragma unroll
  for (int i = 1; i < 8; ++i) M = fmaxf(M, red1[i]);
  float e = (tid < Pp) ? expf(x - M) : 0.f;
  float s = allred(e);
  if ((tid & 63) == 0) red2[tid >> 6] = s;
  __syncthreads();
  float S = 0.f;
  #pragma unroll
  for (int i = 0; i < 8; ++i) S += red2[i];
  if (tid < Pp) o[tid] = (x - M) - logf(S);
}

// ---------------------------------------------------------------------------
extern "C" void kernel_launch(void* const* d_in, const int* in_sizes, int n_in,
                              void* d_out, int out_size, void* d_ws, size_t ws_size,
                              hipStream_t stream){
  const int*   passage  = (const int*)d_in[0];
  const int*   question = (const int*)d_in[1];
  const float* emb      = (const float*)d_in[2];
  const float* pW_ih    = (const float*)d_in[3];
  const float* pW_hh    = (const float*)d_in[4];
  const float* pb_ih    = (const float*)d_in[5];
  const float* pb_hh    = (const float*)d_in[6];
  const float* qW_ih    = (const float*)d_in[7];
  const float* qW_hh    = (const float*)d_in[8];
  const float* qb_ih    = (const float*)d_in[9];
  const float* qb_hh    = (const float*)d_in[10];
  const float* start_w  = (const float*)d_in[11];
  const float* start_b  = (const float*)d_in[12];
  const float* end_w    = (const float*)d_in[13];
  const float* end_b    = (const float*)d_in[14];
  float* out = (float*)d_out;

  // workspace layout (float-sized units)
  float*     ws    = (float*)d_ws;
  unsigned*  w16   = (unsigned*)ws;                    //   393216 u32
  _Float16*  emb16 = (_Float16*)(ws + 393216);         // 32,000,000 halfs = 16,000,000 f
  _Float16*  wih16 = (_Float16*)(ws + 16393216);       //   983040 halfs  =   491520 f
  _Float16*  xpp   = (_Float16*)(ws + 16884736);       // 39321600 halfs  = 19660800 f
  _Float16*  xpq   = (_Float16*)(ws + 36545536);       //  4915200 halfs  =  2457600 f
  float*     Hp    = ws + 39003136;                    // 13107200 f
  float*     Hq    = ws + 52110336;                    //  1638400 f
  // total 53,748,736 floats = 215 MB

  hipLaunchKernelGGL(prep_w16, dim3(1536), dim3(256), 0, stream, pW_hh, qW_hh, w16);
  hipLaunchKernelGGL(prep_emb16, dim3(62500), dim3(256), 0, stream, emb, emb16);
  hipLaunchKernelGGL(prep_wih16, dim3(1920), dim3(256), 0, stream, pW_ih, qW_ih, wih16);
  hipLaunchKernelGGL(xproj_mfma, dim3(12, 200), dim3(512), 0, stream,
                     passage, emb16, wih16, pb_ih, xpp, Pp);
  hipLaunchKernelGGL(xproj_mfma, dim3(12, 25), dim3(512), 0, stream,
                     question, emb16, wih16 + (size_t)2 * H3 * 320, qb_ih, xpq, Qq);
  hipLaunchKernelGGL(gru_kernel, dim3(256), dim3(512), 0, stream,
                     passage, question, xpp, xpq, w16, pb_hh, qb_hh, Hp, Hq);
  size_t attn_lds = (size_t)(Qq * Dd + 64 + 64 + 512 + 512) * sizeof(float);
  hipLaunchKernelGGL(attn_kernel, dim3(4, 64), dim3(512), attn_lds, stream,
                     Hp, Hq, passage, question, start_w, start_b, end_w, end_b, out);
  hipLaunchKernelGGL(lsm_kernel, dim3(128), dim3(512), 0, stream, passage, out);
}